// Round 1
// baseline (391.252 us; speedup 1.0000x reference)
//
#include <hip/hip_runtime.h>
#include <hip/hip_bf16.h>

#define NBATCH 2
#define SEQ    2048
#define DMODEL 1024
#define NHEAD  16
#define DHEAD  64
#define NHTOT  (NBATCH*NHEAD)   // 32

typedef __attribute__((ext_vector_type(8))) short          short8;
typedef __attribute__((ext_vector_type(4))) float          f32x4;
typedef __attribute__((ext_vector_type(4))) unsigned short ushort4v;

__device__ __forceinline__ unsigned short f2bf(float x) {
  union { __hip_bfloat16 b; unsigned short u; } c;
  c.b = __float2bfloat16(x);
  return c.u;
}

// ---------------------------------------------------------------------------
// Kernel 1: Q,K fp32 -> bf16, per-head layout [NH][L][DK]; Q pre-scaled by
// log2(e)/sqrt(DK) so softmax = exp2(s - max).
// ---------------------------------------------------------------------------
__global__ __launch_bounds__(256) void cvt_qk(const float* __restrict__ q,
                                              const float* __restrict__ k,
                                              unsigned short* __restrict__ qb,
                                              unsigned short* __restrict__ kb) {
  const float QSCALE = 0.125f * 1.44269504088896340736f;  // log2(e)/sqrt(64)
  int e = (blockIdx.x * 256 + threadIdx.x) * 4;           // 4 floats/thread
  int n = e >> 21;                 // / (SEQ*DMODEL)
  int r = e & ((1 << 21) - 1);
  int l = r >> 10;                 // / DMODEL
  int c = r & 1023;
  int h = c >> 6;
  int d = c & 63;
  size_t dst = ((size_t)(n * NHEAD + h) * SEQ + l) * DHEAD + d;
  float4 qv = *reinterpret_cast<const float4*>(q + e);
  float4 kv = *reinterpret_cast<const float4*>(k + e);
  ushort4v qo, ko;
  qo.x = f2bf(qv.x * QSCALE); qo.y = f2bf(qv.y * QSCALE);
  qo.z = f2bf(qv.z * QSCALE); qo.w = f2bf(qv.w * QSCALE);
  ko.x = f2bf(kv.x); ko.y = f2bf(kv.y); ko.z = f2bf(kv.z); ko.w = f2bf(kv.w);
  *reinterpret_cast<ushort4v*>(qb + dst) = qo;
  *reinterpret_cast<ushort4v*>(kb + dst) = ko;
}

// ---------------------------------------------------------------------------
// Kernel 2: V fp32 -> bf16 transposed per head: Vt[NH][DK][L]
// 64(l) x 64(d) tile transpose through LDS.
// ---------------------------------------------------------------------------
__global__ __launch_bounds__(256) void vtrans(const float* __restrict__ v,
                                              unsigned short* __restrict__ vt) {
  __shared__ unsigned short t[64][66];   // +2 pad: conflict-free column reads
  int bid = blockIdx.x;
  int nh = bid >> 5;        // / (SEQ/64)
  int lt = bid & 31;
  int n = nh >> 4, h = nh & 15;
  int lbase = lt * 64;
  #pragma unroll
  for (int j = 0; j < 16; ++j) {
    int e = j * 256 + threadIdx.x;
    int l = e >> 6, d = e & 63;
    float x = v[((size_t)n * SEQ + lbase + l) * DMODEL + h * DHEAD + d];
    t[l][d] = f2bf(x);
  }
  __syncthreads();
  #pragma unroll
  for (int j = 0; j < 16; ++j) {
    int e = j * 256 + threadIdx.x;
    int d = e >> 6, l = e & 63;
    vt[((size_t)nh * DHEAD + d) * SEQ + lbase + l] = t[l][d];
  }
}

// ---------------------------------------------------------------------------
// Kernel 3: fc weight fp32 -> bf16 (layout unchanged [DMODEL][DMODEL])
// ---------------------------------------------------------------------------
__global__ __launch_bounds__(256) void cvt_w(const float* __restrict__ w,
                                             unsigned short* __restrict__ wb) {
  int e = (blockIdx.x * 256 + threadIdx.x) * 4;
  float4 wv = *reinterpret_cast<const float4*>(w + e);
  ushort4v wo;
  wo.x = f2bf(wv.x); wo.y = f2bf(wv.y); wo.z = f2bf(wv.z); wo.w = f2bf(wv.w);
  *reinterpret_cast<ushort4v*>(wb + e) = wo;
}

// ---------------------------------------------------------------------------
// Kernel 4: flash attention. 1 block = 4 waves; wave owns 16 q-rows.
// Per (n,h): S = Qs K^T (pre-scaled, exp2 domain), online softmax, O = P V.
// MFMA 16x16x32 bf16. A-frag: lane -> row l&15, k = (l>>4)*8..+7.
// B-frag: lane -> col l&15, k = (l>>4)*8..+7. C/D: col l&15, row (l>>4)*4+r.
// ---------------------------------------------------------------------------
__global__ __launch_bounds__(256) void attn_fwd(const unsigned short* __restrict__ Qb,
                                                const unsigned short* __restrict__ Kb,
                                                const unsigned short* __restrict__ Vt,
                                                unsigned short* __restrict__ Ab) {
  __shared__ __align__(16) unsigned short pbuf[4][16][64];  // per-wave P tile
  int bid = blockIdx.x;
  int nh = bid >> 5;        // 32 q-tiles per (n,h)
  int qt = bid & 31;
  int wave = threadIdx.x >> 6;
  int lane = threadIdx.x & 63;
  int l15 = lane & 15, l4 = lane >> 4;

  const unsigned short* Qrow =
      Qb + ((size_t)nh * SEQ + qt * 64 + wave * 16 + l15) * DHEAD + l4 * 8;
  short8 aq0 = *reinterpret_cast<const short8*>(Qrow);
  short8 aq1 = *reinterpret_cast<const short8*>(Qrow + 32);

  const unsigned short* Kb_nh = Kb + (size_t)nh * SEQ * DHEAD;
  const unsigned short* Vt_nh = Vt + (size_t)nh * DHEAD * SEQ;

  float m_run[4], l_run[4], corr[4];
  f32x4 acc[4];
  #pragma unroll
  for (int r = 0; r < 4; ++r) { m_run[r] = -3.0e38f; l_run[r] = 0.f; }
  #pragma unroll
  for (int d = 0; d < 4; ++d) acc[d] = (f32x4){0.f, 0.f, 0.f, 0.f};

  for (int kk = 0; kk < SEQ; kk += 64) {
    // ---- S tile: 16 q x 64 keys (4 MFMA-tiles x K=64) ----
    f32x4 s[4];
    #pragma unroll
    for (int t = 0; t < 4; ++t) {
      const unsigned short* Krow =
          Kb_nh + (size_t)(kk + t * 16 + l15) * DHEAD + l4 * 8;
      short8 bk0 = *reinterpret_cast<const short8*>(Krow);
      short8 bk1 = *reinterpret_cast<const short8*>(Krow + 32);
      f32x4 z = (f32x4){0.f, 0.f, 0.f, 0.f};
      z = __builtin_amdgcn_mfma_f32_16x16x32_bf16(aq0, bk0, z, 0, 0, 0);
      z = __builtin_amdgcn_mfma_f32_16x16x32_bf16(aq1, bk1, z, 0, 0, 0);
      s[t] = z;
    }
    // ---- online softmax stats (rows m = l4*4+r, cols spread over 16 lanes) --
    #pragma unroll
    for (int r = 0; r < 4; ++r) {
      float mx = fmaxf(fmaxf(s[0][r], s[1][r]), fmaxf(s[2][r], s[3][r]));
      #pragma unroll
      for (int off = 1; off < 16; off <<= 1)
        mx = fmaxf(mx, __shfl_xor(mx, off));
      float mnew = fmaxf(m_run[r], mx);
      corr[r] = exp2f(m_run[r] - mnew);
      float sum = 0.f;
      #pragma unroll
      for (int t = 0; t < 4; ++t) {
        float p = exp2f(s[t][r] - mnew);
        s[t][r] = p;
        sum += p;
      }
      #pragma unroll
      for (int off = 1; off < 16; off <<= 1)
        sum += __shfl_xor(sum, off);
      l_run[r] = l_run[r] * corr[r] + sum;
      m_run[r] = mnew;
    }
    #pragma unroll
    for (int dd = 0; dd < 4; ++dd) {
      #pragma unroll
      for (int r = 0; r < 4; ++r) acc[dd][r] *= corr[r];
    }
    // ---- P: C/D layout -> LDS row-major [16][64] -> A-operand layout ----
    #pragma unroll
    for (int t = 0; t < 4; ++t)
      #pragma unroll
      for (int r = 0; r < 4; ++r)
        pbuf[wave][l4 * 4 + r][t * 16 + l15] = f2bf(s[t][r]);
    asm volatile("s_waitcnt lgkmcnt(0)" ::: "memory");
    short8 pa0 = *reinterpret_cast<const short8*>(&pbuf[wave][l15][l4 * 8]);
    short8 pa1 = *reinterpret_cast<const short8*>(&pbuf[wave][l15][32 + l4 * 8]);
    // ---- PV: out[16 q][64 d], B-operand from Vt rows (contiguous keys) ----
    #pragma unroll
    for (int dd = 0; dd < 4; ++dd) {
      const unsigned short* Vrow =
          Vt_nh + (size_t)(dd * 16 + l15) * SEQ + kk + l4 * 8;
      short8 bv0 = *reinterpret_cast<const short8*>(Vrow);
      short8 bv1 = *reinterpret_cast<const short8*>(Vrow + 32);
      acc[dd] = __builtin_amdgcn_mfma_f32_16x16x32_bf16(pa0, bv0, acc[dd], 0, 0, 0);
      acc[dd] = __builtin_amdgcn_mfma_f32_16x16x32_bf16(pa1, bv1, acc[dd], 0, 0, 0);
    }
  }
  // ---- epilogue: O /= l, write bf16 to Ab[N*SEQ][DMODEL] ----
  int n = nh >> 4, h = nh & 15;
  size_t obase =
      ((size_t)n * SEQ + qt * 64 + wave * 16 + l4 * 4) * DMODEL + h * DHEAD;
  #pragma unroll
  for (int dd = 0; dd < 4; ++dd) {
    #pragma unroll
    for (int r = 0; r < 4; ++r) {
      float o = acc[dd][r] / l_run[r];
      Ab[obase + (size_t)r * DMODEL + dd * 16 + l15] = f2bf(o);
    }
  }
}

// ---------------------------------------------------------------------------
// Kernel 5: out[4096][1024] = Ab(bf16) @ Wb^T + bias, fp32 out.
// 64x64 block tile, 4 waves (2x2), each wave 32x32 via 2x2 16x16 MFMA tiles.
// ---------------------------------------------------------------------------
__global__ __launch_bounds__(256) void fc_gemm(const unsigned short* __restrict__ Ab,
                                               const unsigned short* __restrict__ Wb,
                                               const float* __restrict__ bias,
                                               float* __restrict__ out) {
  int bid = blockIdx.x;
  int bm = bid >> 4;        // 64 M-blocks
  int bn = bid & 15;        // 16 N-blocks
  int wave = threadIdx.x >> 6, lane = threadIdx.x & 63;
  int wr = wave >> 1, wc = wave & 1;
  int l15 = lane & 15, l4 = lane >> 4;
  int mbase = bm * 64 + wr * 32;
  int nbase = bn * 64 + wc * 32;

  f32x4 acc[2][2];
  #pragma unroll
  for (int i = 0; i < 2; ++i)
    #pragma unroll
    for (int j = 0; j < 2; ++j) acc[i][j] = (f32x4){0.f, 0.f, 0.f, 0.f};

  const unsigned short* Arow0 = Ab + (size_t)(mbase + l15) * DMODEL + l4 * 8;
  const unsigned short* Arow1 = Arow0 + 16 * DMODEL;
  const unsigned short* Brow0 = Wb + (size_t)(nbase + l15) * DMODEL + l4 * 8;
  const unsigned short* Brow1 = Brow0 + 16 * DMODEL;

  for (int k0 = 0; k0 < DMODEL; k0 += 32) {
    short8 a0 = *reinterpret_cast<const short8*>(Arow0 + k0);
    short8 a1 = *reinterpret_cast<const short8*>(Arow1 + k0);
    short8 b0 = *reinterpret_cast<const short8*>(Brow0 + k0);
    short8 b1 = *reinterpret_cast<const short8*>(Brow1 + k0);
    acc[0][0] = __builtin_amdgcn_mfma_f32_16x16x32_bf16(a0, b0, acc[0][0], 0, 0, 0);
    acc[0][1] = __builtin_amdgcn_mfma_f32_16x16x32_bf16(a0, b1, acc[0][1], 0, 0, 0);
    acc[1][0] = __builtin_amdgcn_mfma_f32_16x16x32_bf16(a1, b0, acc[1][0], 0, 0, 0);
    acc[1][1] = __builtin_amdgcn_mfma_f32_16x16x32_bf16(a1, b1, acc[1][1], 0, 0, 0);
  }

  #pragma unroll
  for (int ms = 0; ms < 2; ++ms) {
    #pragma unroll
    for (int ns = 0; ns < 2; ++ns) {
      int col = nbase + ns * 16 + l15;
      float bv = bias[col];
      #pragma unroll
      for (int r = 0; r < 4; ++r) {
        int row = mbase + ms * 16 + l4 * 4 + r;
        out[(size_t)row * DMODEL + col] = acc[ms][ns][r] + bv;
      }
    }
  }
}

// ---------------------------------------------------------------------------
extern "C" void kernel_launch(void* const* d_in, const int* in_sizes, int n_in,
                              void* d_out, int out_size, void* d_ws, size_t ws_size,
                              hipStream_t stream) {
  const float* values  = (const float*)d_in[0];
  const float* keys    = (const float*)d_in[1];
  const float* queries = (const float*)d_in[2];
  const float* fc_w    = (const float*)d_in[3];
  const float* fc_b    = (const float*)d_in[4];
  float* out = (float*)d_out;

  char* ws = (char*)d_ws;
  const size_t QKV_BYTES = (size_t)NHTOT * SEQ * DHEAD * 2;  // 8 MB each
  unsigned short* Qb = (unsigned short*)(ws);
  unsigned short* Kb = (unsigned short*)(ws + QKV_BYTES);
  unsigned short* Vt = (unsigned short*)(ws + 2 * QKV_BYTES);
  unsigned short* Wb = (unsigned short*)(ws + 3 * QKV_BYTES);
  unsigned short* Ab = (unsigned short*)(ws + 3 * QKV_BYTES + (size_t)DMODEL * DMODEL * 2);

  // 1+3. conversions
  cvt_qk<<<4096, 256, 0, stream>>>(queries, keys, Qb, Kb);
  vtrans<<<1024, 256, 0, stream>>>(values, Vt);
  cvt_w<<<1024, 256, 0, stream>>>(fc_w, Wb);
  // 4. flash attention
  attn_fwd<<<NHTOT * (SEQ / 64), 256, 0, stream>>>(Qb, Kb, Vt, Ab);
  // 5. output projection
  fc_gemm<<<(NBATCH * SEQ / 64) * (DMODEL / 64), 256, 0, stream>>>(Ab, Wb, fc_b, out);
}

// Round 2
// 220.148 us; speedup vs baseline: 1.7772x; 1.7772x over previous
//
#include <hip/hip_runtime.h>
#include <hip/hip_bf16.h>

#define NBATCH 2
#define SEQ    2048
#define DMODEL 1024
#define NHEAD  16
#define DHEAD  64
#define NHTOT  (NBATCH*NHEAD)   // 32

typedef __attribute__((ext_vector_type(8))) short          short8;
typedef __attribute__((ext_vector_type(4))) float          f32x4;
typedef __attribute__((ext_vector_type(4))) unsigned short ushort4v;

__device__ __forceinline__ unsigned short f2bf(float x) {
  union { __hip_bfloat16 b; unsigned short u; } c;
  c.b = __float2bfloat16(x);
  return c.u;
}

// async global->LDS, 16B per lane; LDS dest must be wave-uniform base (+lane*16)
__device__ __forceinline__ void gl_lds16(const unsigned short* g, unsigned short* l) {
  __builtin_amdgcn_global_load_lds(
      (const __attribute__((address_space(1))) void*)g,
      (__attribute__((address_space(3))) void*)l, 16, 0, 0);
}

// ---------------------------------------------------------------------------
// Kernel 1: Q,K fp32 -> bf16, per-head layout [NH][L][DK]; Q pre-scaled by
// log2(e)/sqrt(DK) so softmax = exp2(s - max).
// ---------------------------------------------------------------------------
__global__ __launch_bounds__(256) void cvt_qk(const float* __restrict__ q,
                                              const float* __restrict__ k,
                                              unsigned short* __restrict__ qb,
                                              unsigned short* __restrict__ kb) {
  const float QSCALE = 0.125f * 1.44269504088896340736f;  // log2(e)/sqrt(64)
  int e = (blockIdx.x * 256 + threadIdx.x) * 4;
  int n = e >> 21;
  int r = e & ((1 << 21) - 1);
  int l = r >> 10;
  int c = r & 1023;
  int h = c >> 6;
  int d = c & 63;
  size_t dst = ((size_t)(n * NHEAD + h) * SEQ + l) * DHEAD + d;
  float4 qv = *reinterpret_cast<const float4*>(q + e);
  float4 kv = *reinterpret_cast<const float4*>(k + e);
  ushort4v qo, ko;
  qo.x = f2bf(qv.x * QSCALE); qo.y = f2bf(qv.y * QSCALE);
  qo.z = f2bf(qv.z * QSCALE); qo.w = f2bf(qv.w * QSCALE);
  ko.x = f2bf(kv.x); ko.y = f2bf(kv.y); ko.z = f2bf(kv.z); ko.w = f2bf(kv.w);
  *reinterpret_cast<ushort4v*>(qb + dst) = qo;
  *reinterpret_cast<ushort4v*>(kb + dst) = ko;
}

// ---------------------------------------------------------------------------
// Kernel 2: V fp32 -> bf16 transposed per head: Vt[NH][DK][L]
// ---------------------------------------------------------------------------
__global__ __launch_bounds__(256) void vtrans(const float* __restrict__ v,
                                              unsigned short* __restrict__ vt) {
  __shared__ unsigned short t[64][66];
  int bid = blockIdx.x;
  int nh = bid >> 5;
  int lt = bid & 31;
  int n = nh >> 4, h = nh & 15;
  int lbase = lt * 64;
  #pragma unroll
  for (int j = 0; j < 16; ++j) {
    int e = j * 256 + threadIdx.x;
    int l = e >> 6, d = e & 63;
    float x = v[((size_t)n * SEQ + lbase + l) * DMODEL + h * DHEAD + d];
    t[l][d] = f2bf(x);
  }
  __syncthreads();
  #pragma unroll
  for (int j = 0; j < 16; ++j) {
    int e = j * 256 + threadIdx.x;
    int d = e >> 6, l = e & 63;
    vt[((size_t)nh * DHEAD + d) * SEQ + lbase + l] = t[l][d];
  }
}

// ---------------------------------------------------------------------------
// Kernel 3: fc weight fp32 -> bf16 (layout unchanged [DMODEL][DMODEL])
// ---------------------------------------------------------------------------
__global__ __launch_bounds__(256) void cvt_w(const float* __restrict__ w,
                                             unsigned short* __restrict__ wb) {
  int e = (blockIdx.x * 256 + threadIdx.x) * 4;
  float4 wv = *reinterpret_cast<const float4*>(w + e);
  ushort4v wo;
  wo.x = f2bf(wv.x); wo.y = f2bf(wv.y); wo.z = f2bf(wv.z); wo.w = f2bf(wv.w);
  *reinterpret_cast<ushort4v*>(wb + e) = wo;
}

// ---------------------------------------------------------------------------
// Kernel 4: flash attention, 2-phase double-buffered K/V LDS staging.
// Swapped QK^T: S = mfma(A=K, B=Q) -> lane owns q = lane&15, keys
// t*16 + (lane>>4)*4 + r. Softmax per-lane + 2 shuffles. P packed bf16 via
// 4x ds_write_b64 into pbuf[16][72] (conflict-free), re-read as PV A-frag.
// K/V tiles [64 rows][128 B] staged with 16B-chunk XOR swizzle
// (chunk ^= row&7) so frag ds_read_b128 is bank-conflict-free.
// ---------------------------------------------------------------------------
__global__ __launch_bounds__(256) void attn_fwd(const unsigned short* __restrict__ Qb,
                                                const unsigned short* __restrict__ Kb,
                                                const unsigned short* __restrict__ Vt,
                                                unsigned short* __restrict__ Ab) {
  __shared__ __align__(16) unsigned short kbuf[2][64 * 64];
  __shared__ __align__(16) unsigned short vbuf[2][64 * 64];
  __shared__ __align__(16) unsigned short pbuf[4][16][72];

  const int bid = blockIdx.x;
  const int nh = bid >> 5;
  const int qt = bid & 31;
  const int tid = threadIdx.x;
  const int wave = tid >> 6;
  const int lane = tid & 63;
  const int l15 = lane & 15, l4 = lane >> 4;

  const unsigned short* Kb_nh = Kb + (size_t)nh * SEQ * DHEAD;
  const unsigned short* Vt_nh = Vt + (size_t)nh * DHEAD * SEQ;

  // Q fragment (B-operand): B[k=d][col=q] = Q[q=l15][d = l4*8+j], halves 0/32
  const unsigned short* Qrow =
      Qb + ((size_t)nh * SEQ + qt * 64 + wave * 16 + l15) * DHEAD + l4 * 8;
  short8 bq0 = *reinterpret_cast<const short8*>(Qrow);
  short8 bq1 = *reinterpret_cast<const short8*>(Qrow + 32);

  float m_run = -3.0e38f, l_run = 0.f;
  f32x4 acc[4];
  #pragma unroll
  for (int d = 0; d < 4; ++d) acc[d] = (f32x4){0.f, 0.f, 0.f, 0.f};

  auto stage = [&](int buf, int kk) {
    #pragma unroll
    for (int j = 0; j < 2; ++j) {
      int c = j * 256 + tid;           // chunk index 0..511 (16B chunks)
      int row = c >> 3, cs = c & 7;
      int cg = cs ^ (row & 7);         // inverse-swizzled global chunk
      int cb = j * 256 + (tid & 192);  // wave-uniform LDS chunk base
      gl_lds16(Kb_nh + (size_t)(kk + row) * DHEAD + cg * 8, &kbuf[buf][cb * 8]);
      gl_lds16(Vt_nh + (size_t)row * SEQ + kk + cg * 8, &vbuf[buf][cb * 8]);
    }
  };

  stage(0, 0);
  __syncthreads();

  const int NT = SEQ / 64;
  for (int it = 0; it < NT; ++it) {
    int cur = it & 1;
    if (it + 1 < NT) stage(cur ^ 1, (it + 1) * 64);

    const unsigned short* kb = kbuf[cur];
    const unsigned short* vb = vbuf[cur];

    // ---- QK^T (swapped): s[t][r] = S[key = t*16 + l4*4 + r][q = l15] ----
    f32x4 s[4];
    #pragma unroll
    for (int t = 0; t < 4; ++t) {
      int row = t * 16 + l15;
      int sw = row & 7;
      short8 ak0 = *reinterpret_cast<const short8*>(kb + row * 64 + ((l4 ^ sw) * 8));
      short8 ak1 = *reinterpret_cast<const short8*>(kb + row * 64 + (((l4 + 4) ^ sw) * 8));
      f32x4 z = (f32x4){0.f, 0.f, 0.f, 0.f};
      z = __builtin_amdgcn_mfma_f32_16x16x32_bf16(ak0, bq0, z, 0, 0, 0);
      z = __builtin_amdgcn_mfma_f32_16x16x32_bf16(ak1, bq1, z, 0, 0, 0);
      s[t] = z;
    }

    // ---- online softmax: lane owns q = l15 (16 of 64 keys; group of 4 lanes)
    float mx = s[0][0];
    #pragma unroll
    for (int t = 0; t < 4; ++t)
      #pragma unroll
      for (int r = 0; r < 4; ++r) mx = fmaxf(mx, s[t][r]);
    mx = fmaxf(mx, __shfl_xor(mx, 16));
    mx = fmaxf(mx, __shfl_xor(mx, 32));
    float mnew = fmaxf(m_run, mx);
    float corr = exp2f(m_run - mnew);
    m_run = mnew;
    float sum = 0.f;
    #pragma unroll
    for (int t = 0; t < 4; ++t)
      #pragma unroll
      for (int r = 0; r < 4; ++r) {
        float p = exp2f(s[t][r] - mnew);
        s[t][r] = p;
        sum += p;
      }
    sum += __shfl_xor(sum, 16);
    sum += __shfl_xor(sum, 32);
    l_run = l_run * corr + sum;

    // acc holds O[q = l4*4 + r][d]; fetch corr for those q's and rescale
    #pragma unroll
    for (int r = 0; r < 4; ++r) {
      float cb_ = __shfl(corr, l4 * 4 + r);
      #pragma unroll
      for (int dd = 0; dd < 4; ++dd) acc[dd][r] *= cb_;
    }

    // ---- P -> bf16 -> pbuf[q][key] (4x ds_write_b64, conflict-free) ----
    #pragma unroll
    for (int t = 0; t < 4; ++t) {
      ushort4v pk;
      pk.x = f2bf(s[t][0]); pk.y = f2bf(s[t][1]);
      pk.z = f2bf(s[t][2]); pk.w = f2bf(s[t][3]);
      *reinterpret_cast<ushort4v*>(&pbuf[wave][l15][t * 16 + l4 * 4]) = pk;
    }
    asm volatile("s_waitcnt lgkmcnt(0)" ::: "memory");
    __builtin_amdgcn_sched_barrier(0);
    short8 pa0 = *reinterpret_cast<const short8*>(&pbuf[wave][l15][l4 * 8]);
    short8 pa1 = *reinterpret_cast<const short8*>(&pbuf[wave][l15][32 + l4 * 8]);

    // ---- PV: acc[dd] += P[q][k] * V[k][d], B-frag from Vt tile rows ----
    #pragma unroll
    for (int dd = 0; dd < 4; ++dd) {
      int row = dd * 16 + l15;
      int sw = row & 7;
      short8 bv0 = *reinterpret_cast<const short8*>(vb + row * 64 + ((l4 ^ sw) * 8));
      short8 bv1 = *reinterpret_cast<const short8*>(vb + row * 64 + (((l4 + 4) ^ sw) * 8));
      acc[dd] = __builtin_amdgcn_mfma_f32_16x16x32_bf16(pa0, bv0, acc[dd], 0, 0, 0);
      acc[dd] = __builtin_amdgcn_mfma_f32_16x16x32_bf16(pa1, bv1, acc[dd], 0, 0, 0);
    }
    __syncthreads();
  }

  // ---- epilogue: O /= l (l lives in lanes 0..15), write bf16 ----
  int n = nh >> 4, hd = nh & 15;
  #pragma unroll
  for (int r = 0; r < 4; ++r) {
    float lf = __shfl(l_run, l4 * 4 + r);
    float inv = 1.0f / lf;
    size_t ob = ((size_t)n * SEQ + qt * 64 + wave * 16 + l4 * 4 + r) * DMODEL +
                hd * DHEAD;
    #pragma unroll
    for (int dd = 0; dd < 4; ++dd)
      Ab[ob + dd * 16 + l15] = f2bf(acc[dd][r] * inv);
  }
}

// ---------------------------------------------------------------------------
// Kernel 5: out = Ab(bf16) @ Wb^T + bias. 64x64 tile, BK=32, 2-phase
// double-buffered LDS staging via global_load_lds (linear, 64B rows ->
// conflict-free without swizzle). 4 waves (2x2), wave = 32x32 out.
// ---------------------------------------------------------------------------
__global__ __launch_bounds__(256) void fc_gemm(const unsigned short* __restrict__ Ab,
                                               const unsigned short* __restrict__ Wb,
                                               const float* __restrict__ bias,
                                               float* __restrict__ out) {
  __shared__ __align__(16) unsigned short At[2][64 * 32];
  __shared__ __align__(16) unsigned short Bt[2][64 * 32];
  const int bid = blockIdx.x;
  const int bm = bid >> 4;   // 4096/64 = 64 m-blocks
  const int bn = bid & 15;   // 1024/64 = 16 n-blocks
  const int tid = threadIdx.x;
  const int wave = tid >> 6, lane = tid & 63;
  const int wr = wave >> 1, wc = wave & 1;
  const int l15 = lane & 15, l4 = lane >> 4;

  f32x4 acc[2][2];
  #pragma unroll
  for (int i = 0; i < 2; ++i)
    #pragma unroll
    for (int j = 0; j < 2; ++j) acc[i][j] = (f32x4){0.f, 0.f, 0.f, 0.f};

  auto stage = [&](int buf, int k0) {
    int row = tid >> 2, cs = tid & 3;       // 256 chunks per tile
    int cb = tid & 192;                     // wave-uniform chunk base
    gl_lds16(Ab + (size_t)(bm * 64 + row) * DMODEL + k0 + cs * 8, &At[buf][cb * 8]);
    gl_lds16(Wb + (size_t)(bn * 64 + row) * DMODEL + k0 + cs * 8, &Bt[buf][cb * 8]);
  };

  stage(0, 0);
  __syncthreads();

  const int NT = DMODEL / 32;
  for (int it = 0; it < NT; ++it) {
    int cur = it & 1;
    if (it + 1 < NT) stage(cur ^ 1, (it + 1) * 32);

    short8 a0 = *reinterpret_cast<const short8*>(&At[cur][(wr * 32 + l15) * 32 + l4 * 8]);
    short8 a1 = *reinterpret_cast<const short8*>(&At[cur][(wr * 32 + 16 + l15) * 32 + l4 * 8]);
    short8 b0 = *reinterpret_cast<const short8*>(&Bt[cur][(wc * 32 + l15) * 32 + l4 * 8]);
    short8 b1 = *reinterpret_cast<const short8*>(&Bt[cur][(wc * 32 + 16 + l15) * 32 + l4 * 8]);
    acc[0][0] = __builtin_amdgcn_mfma_f32_16x16x32_bf16(a0, b0, acc[0][0], 0, 0, 0);
    acc[0][1] = __builtin_amdgcn_mfma_f32_16x16x32_bf16(a0, b1, acc[0][1], 0, 0, 0);
    acc[1][0] = __builtin_amdgcn_mfma_f32_16x16x32_bf16(a1, b0, acc[1][0], 0, 0, 0);
    acc[1][1] = __builtin_amdgcn_mfma_f32_16x16x32_bf16(a1, b1, acc[1][1], 0, 0, 0);
    __syncthreads();
  }

  #pragma unroll
  for (int m = 0; m < 2; ++m)
    #pragma unroll
    for (int nn = 0; nn < 2; ++nn) {
      int col = bn * 64 + wc * 32 + nn * 16 + l15;
      float bv = bias[col];
      #pragma unroll
      for (int r = 0; r < 4; ++r) {
        int row = bm * 64 + wr * 32 + m * 16 + l4 * 4 + r;
        out[(size_t)row * DMODEL + col] = acc[m][nn][r] + bv;
      }
    }
}

// ---------------------------------------------------------------------------
extern "C" void kernel_launch(void* const* d_in, const int* in_sizes, int n_in,
                              void* d_out, int out_size, void* d_ws, size_t ws_size,
                              hipStream_t stream) {
  const float* values  = (const float*)d_in[0];
  const float* keys    = (const float*)d_in[1];
  const float* queries = (const float*)d_in[2];
  const float* fc_w    = (const float*)d_in[3];
  const float* fc_b    = (const float*)d_in[4];
  float* out = (float*)d_out;

  char* ws = (char*)d_ws;
  const size_t QKV_BYTES = (size_t)NHTOT * SEQ * DHEAD * 2;  // 8 MB each
  unsigned short* Qb = (unsigned short*)(ws);
  unsigned short* Kb = (unsigned short*)(ws + QKV_BYTES);
  unsigned short* Vt = (unsigned short*)(ws + 2 * QKV_BYTES);
  unsigned short* Wb = (unsigned short*)(ws + 3 * QKV_BYTES);
  unsigned short* Ab = (unsigned short*)(ws + 3 * QKV_BYTES + (size_t)DMODEL * DMODEL * 2);

  cvt_qk<<<4096, 256, 0, stream>>>(queries, keys, Qb, Kb);
  vtrans<<<1024, 256, 0, stream>>>(values, Vt);
  cvt_w<<<1024, 256, 0, stream>>>(fc_w, Wb);
  attn_fwd<<<NHTOT * (SEQ / 64), 256, 0, stream>>>(Qb, Kb, Vt, Ab);
  fc_gemm<<<(NBATCH * SEQ / 64) * (DMODEL / 64), 256, 0, stream>>>(Ab, Wb, fc_b, out);
}

// Round 3
// 198.263 us; speedup vs baseline: 1.9734x; 1.1104x over previous
//
#include <hip/hip_runtime.h>
#include <hip/hip_bf16.h>

#define NBATCH 2
#define SEQ    2048
#define DMODEL 1024
#define NHEAD  16
#define DHEAD  64
#define NHTOT  (NBATCH*NHEAD)   // 32

typedef __attribute__((ext_vector_type(8)))  short          short8;
typedef __attribute__((ext_vector_type(4)))  float          f32x4;
typedef __attribute__((ext_vector_type(16))) float          f32x16;
typedef __attribute__((ext_vector_type(4)))  unsigned short ushort4v;

__device__ __forceinline__ unsigned short f2bf(float x) {
  union { __hip_bfloat16 b; unsigned short u; } c;
  c.b = __float2bfloat16(x);
  return c.u;
}

__device__ __forceinline__ unsigned int cvt_pk_bf16(float lo, float hi) {
  unsigned int r;
  asm("v_cvt_pk_bf16_f32 %0, %1, %2" : "=v"(r) : "v"(lo), "v"(hi));
  return r;
}

// async global->LDS, 16B per lane; LDS dest = wave-uniform base + lane*16
__device__ __forceinline__ void gl_lds16(const unsigned short* g, unsigned short* l) {
  __builtin_amdgcn_global_load_lds(
      (const __attribute__((address_space(1))) void*)g,
      (__attribute__((address_space(3))) void*)l, 16, 0, 0);
}

// ---------------------------------------------------------------------------
// Kernel 1: Q,K fp32 -> bf16, per-head layout [NH][L][DK]; Q pre-scaled by
// log2(e)/sqrt(DK) so softmax = exp2(s - max).
// ---------------------------------------------------------------------------
__global__ __launch_bounds__(256) void cvt_qk(const float* __restrict__ q,
                                              const float* __restrict__ k,
                                              unsigned short* __restrict__ qb,
                                              unsigned short* __restrict__ kb) {
  const float QSCALE = 0.125f * 1.44269504088896340736f;  // log2(e)/sqrt(64)
  int e = (blockIdx.x * 256 + threadIdx.x) * 4;
  int n = e >> 21;
  int r = e & ((1 << 21) - 1);
  int l = r >> 10;
  int c = r & 1023;
  int h = c >> 6;
  int d = c & 63;
  size_t dst = ((size_t)(n * NHEAD + h) * SEQ + l) * DHEAD + d;
  float4 qv = *reinterpret_cast<const float4*>(q + e);
  float4 kv = *reinterpret_cast<const float4*>(k + e);
  ushort4v qo, ko;
  qo.x = f2bf(qv.x * QSCALE); qo.y = f2bf(qv.y * QSCALE);
  qo.z = f2bf(qv.z * QSCALE); qo.w = f2bf(qv.w * QSCALE);
  ko.x = f2bf(kv.x); ko.y = f2bf(kv.y); ko.z = f2bf(kv.z); ko.w = f2bf(kv.w);
  *reinterpret_cast<ushort4v*>(qb + dst) = qo;
  *reinterpret_cast<ushort4v*>(kb + dst) = ko;
}

// ---------------------------------------------------------------------------
// Kernel 2: V fp32 -> bf16 transposed per head: Vt[NH][DK][L]
// ---------------------------------------------------------------------------
__global__ __launch_bounds__(256) void vtrans(const float* __restrict__ v,
                                              unsigned short* __restrict__ vt) {
  __shared__ unsigned short t[64][66];
  int bid = blockIdx.x;
  int nh = bid >> 5;
  int lt = bid & 31;
  int n = nh >> 4, h = nh & 15;
  int lbase = lt * 64;
  #pragma unroll
  for (int j = 0; j < 16; ++j) {
    int e = j * 256 + threadIdx.x;
    int l = e >> 6, d = e & 63;
    float x = v[((size_t)n * SEQ + lbase + l) * DMODEL + h * DHEAD + d];
    t[l][d] = f2bf(x);
  }
  __syncthreads();
  #pragma unroll
  for (int j = 0; j < 16; ++j) {
    int e = j * 256 + threadIdx.x;
    int d = e >> 6, l = e & 63;
    vt[((size_t)nh * DHEAD + d) * SEQ + lbase + l] = t[l][d];
  }
}

// ---------------------------------------------------------------------------
// Kernel 3: fc weight fp32 -> bf16
// ---------------------------------------------------------------------------
__global__ __launch_bounds__(256) void cvt_w(const float* __restrict__ w,
                                             unsigned short* __restrict__ wb) {
  int e = (blockIdx.x * 256 + threadIdx.x) * 4;
  float4 wv = *reinterpret_cast<const float4*>(w + e);
  ushort4v wo;
  wo.x = f2bf(wv.x); wo.y = f2bf(wv.y); wo.z = f2bf(wv.z); wo.w = f2bf(wv.w);
  *reinterpret_cast<ushort4v*>(wb + e) = wo;
}

// ---------------------------------------------------------------------------
// Kernel 4: flash attention, 8 waves x QBLK=32, KVBLK=64, mfma_32x32x16.
// Swapped both ways:
//   QK^T: S[key][q] = mfma(A=K, B=Q)  -> C col = q = lane&31
//   PV:   O[d][q]   = mfma(A=Vt, B=P) -> C col = q = lane&31
// so m/l/corr/1-over-l are all lane-local (no shuffles). P built in-register:
// 16 cvt_pk_bf16 + 8 permlane32_swap (T12). Defer-max THR=8 (T13).
// K/V staged via global_load_lds with 16B-chunk XOR swizzle (chunk ^= row&7).
// Epilogue transposes O[d][q] -> row-major via padded LDS, 2 wave-group passes.
// ---------------------------------------------------------------------------
__global__ __launch_bounds__(512, 2) void attn_fwd(const unsigned short* __restrict__ Qb,
                                                   const unsigned short* __restrict__ Kb,
                                                   const unsigned short* __restrict__ Vt,
                                                   unsigned short* __restrict__ Ab) {
  __shared__ __align__(16) unsigned short kbuf[2][64 * 64];
  __shared__ __align__(16) unsigned short vbuf[2][64 * 64];
  __shared__ __align__(16) unsigned short obuf[4][32][72];

  const int bid = blockIdx.x;
  // XCD swizzle (T1): XCD = bid%8 owns 4 full heads -> K/V L2-resident (2MB/XCD)
  const int nh = (bid & 7) * 4 + (bid >> 6);
  const int qt = (bid >> 3) & 7;
  const int tid  = threadIdx.x;
  const int wave = tid >> 6;
  const int lane = tid & 63;
  const int l31  = lane & 31;
  const int hi   = lane >> 5;

  const unsigned short* Kb_nh = Kb + (size_t)nh * SEQ * DHEAD;
  const unsigned short* Vt_nh = Vt + (size_t)nh * DHEAD * SEQ;

  const int qglob = qt * 256 + wave * 32 + l31;

  // Q B-frag: bq[ds] = Q[q=l31][d = ds*16 + hi*8 + j]
  short8 bq[4];
  {
    const unsigned short* Qrow = Qb + ((size_t)nh * SEQ + qglob) * DHEAD + hi * 8;
    #pragma unroll
    for (int ds = 0; ds < 4; ++ds)
      bq[ds] = *reinterpret_cast<const short8*>(Qrow + ds * 16);
  }

  float m_run = -1e30f, l_run = 0.f;
  f32x16 acc[2];
  #pragma unroll
  for (int dt = 0; dt < 2; ++dt)
    #pragma unroll
    for (int r = 0; r < 16; ++r) acc[dt][r] = 0.f;

  auto stage = [&](int buf, int kk) {
    int row = tid >> 3, cs = tid & 7;
    int cg  = cs ^ (row & 7);          // inverse-swizzled global chunk
    int cb  = tid & 448;               // wave-uniform LDS chunk base
    gl_lds16(Kb_nh + (size_t)(kk + row) * DHEAD + cg * 8, &kbuf[buf][cb * 8]);
    gl_lds16(Vt_nh + (size_t)row * SEQ + kk + cg * 8,     &vbuf[buf][cb * 8]);
  };

  stage(0, 0);
  __syncthreads();

  const int NT = SEQ / 64;
  for (int it = 0; it < NT; ++it) {
    const int cur = it & 1;
    if (it + 1 < NT) stage(cur ^ 1, (it + 1) * 64);

    const unsigned short* kb = kbuf[cur];
    const unsigned short* vb = vbuf[cur];

    // ---- QK^T: s[kt] covers keys kt*32 + (r&3)+8*(r>>2)+4*hi, q = l31 ----
    f32x16 s[2];
    #pragma unroll
    for (int kt = 0; kt < 2; ++kt) {
      #pragma unroll
      for (int r = 0; r < 16; ++r) s[kt][r] = 0.f;
      const int row = kt * 32 + l31;
      const int sw  = row & 7;
      const unsigned short* kr = kb + row * 64;
      #pragma unroll
      for (int ds = 0; ds < 4; ++ds) {
        short8 ak = *reinterpret_cast<const short8*>(kr + (((ds * 2 + hi) ^ sw) * 8));
        s[kt] = __builtin_amdgcn_mfma_f32_32x32x16_bf16(ak, bq[ds], s[kt], 0, 0, 0);
      }
    }

    // ---- online softmax, all lane-local (q = l31) ----
    float pmax = s[0][0];
    #pragma unroll
    for (int kt = 0; kt < 2; ++kt)
      #pragma unroll
      for (int r = 0; r < 16; ++r) pmax = fmaxf(pmax, s[kt][r]);
    pmax = fmaxf(pmax, __shfl_xor(pmax, 32));

    if (!__all(pmax - m_run <= 8.0f)) {          // T13 defer-max
      float mnew = fmaxf(m_run, pmax);
      float corr = exp2f(m_run - mnew);
      l_run *= corr;
      #pragma unroll
      for (int dt = 0; dt < 2; ++dt)
        #pragma unroll
        for (int r = 0; r < 16; ++r) acc[dt][r] *= corr;
      m_run = mnew;
    }

    float sum = 0.f;
    #pragma unroll
    for (int kt = 0; kt < 2; ++kt)
      #pragma unroll
      for (int r = 0; r < 16; ++r) {
        float p = exp2f(s[kt][r] - m_run);
        s[kt][r] = p;
        sum += p;
      }
    sum += __shfl_xor(sum, 32);
    l_run += sum;

    // ---- P -> bf16 pairs in-register (T12) ----
    unsigned int pk[2][8];
    #pragma unroll
    for (int kt = 0; kt < 2; ++kt)
      #pragma unroll
      for (int i = 0; i < 8; ++i)
        pk[kt][i] = cvt_pk_bf16(s[kt][2 * i], s[kt][2 * i + 1]);

    // exchange across hi-halves: pa[ks][c] = P[q][k = ks*16 + hi*8 + 2c..2c+1]
    unsigned int pa[4][4];
    #pragma unroll
    for (int ks = 0; ks < 4; ++ks) {
      const int t = ks >> 1, b = (ks & 1) * 4;
      pa[ks][0] = pk[t][b + 0]; pa[ks][2] = pk[t][b + 2];
      asm("v_permlane32_swap_b32 %0, %1" : "+v"(pa[ks][0]), "+v"(pa[ks][2]));
      pa[ks][1] = pk[t][b + 1]; pa[ks][3] = pk[t][b + 3];
      asm("v_permlane32_swap_b32 %0, %1" : "+v"(pa[ks][1]), "+v"(pa[ks][3]));
    }

    // ---- PV: acc[dt] += mfma(A=Vt rows d, B=P) -> O[d][q] ----
    #pragma unroll
    for (int dt = 0; dt < 2; ++dt) {
      const int row = dt * 32 + l31;
      const int sw  = row & 7;
      const unsigned short* vr = vb + row * 64;
      #pragma unroll
      for (int ks = 0; ks < 4; ++ks) {
        short8 av = *reinterpret_cast<const short8*>(vr + (((ks * 2 + hi) ^ sw) * 8));
        union { unsigned int u[4]; short8 s8; } pu;
        pu.u[0] = pa[ks][0]; pu.u[1] = pa[ks][1];
        pu.u[2] = pa[ks][2]; pu.u[3] = pa[ks][3];
        acc[dt] = __builtin_amdgcn_mfma_f32_32x32x16_bf16(av, pu.s8, acc[dt], 0, 0, 0);
      }
    }
    __syncthreads();
  }

  // ---- epilogue: O[d][q]/l -> transpose via LDS -> coalesced bf16 rows ----
  const float inv = 1.0f / l_run;     // lane-local (q = l31)
  const int n = nh >> 4, h = nh & 15;
  #pragma unroll
  for (int pass = 0; pass < 2; ++pass) {
    if ((wave >> 2) == pass) {
      const int w = wave & 3;
      #pragma unroll
      for (int dt = 0; dt < 2; ++dt)
        #pragma unroll
        for (int q4 = 0; q4 < 4; ++q4) {
          ushort4v pv;
          pv.x = f2bf(acc[dt][q4 * 4 + 0] * inv);
          pv.y = f2bf(acc[dt][q4 * 4 + 1] * inv);
          pv.z = f2bf(acc[dt][q4 * 4 + 2] * inv);
          pv.w = f2bf(acc[dt][q4 * 4 + 3] * inv);
          *reinterpret_cast<ushort4v*>(&obuf[w][l31][dt * 32 + q4 * 8 + hi * 4]) = pv;
        }
    }
    __syncthreads();
    #pragma unroll
    for (int rep = 0; rep < 2; ++rep) {
      int idx = rep * 512 + tid;
      int qi = idx >> 3, ch = idx & 7;
      int w = qi >> 5, qr = qi & 31;
      short8 vv = *reinterpret_cast<const short8*>(&obuf[w][qr][ch * 8]);
      size_t orow = (size_t)n * SEQ + qt * 256 + pass * 128 + qi;
      *reinterpret_cast<short8*>(Ab + orow * DMODEL + h * 64 + ch * 8) = vv;
    }
    __syncthreads();
  }
}

// ---------------------------------------------------------------------------
// Kernel 5: out = Ab(bf16) @ Wb^T + bias. m97-style 128x128 tile, BK=32,
// 4 waves (2x2) x 64x64 out (4x4 16x16 tiles): 16 MFMA : 8 ds_read_b128 per
// K-step. Chunk-XOR swizzle (chunk ^= row&3) on [128][32] tiles.
// ---------------------------------------------------------------------------
__global__ __launch_bounds__(256) void fc_gemm(const unsigned short* __restrict__ Ab,
                                               const unsigned short* __restrict__ Wb,
                                               const float* __restrict__ bias,
                                               float* __restrict__ out) {
  __shared__ __align__(16) unsigned short At[2][128 * 32];
  __shared__ __align__(16) unsigned short Bt[2][128 * 32];
  const int bid = blockIdx.x;
  const int bm = bid >> 3;   // 32 m-blocks
  const int bn = bid & 7;    // 8 n-blocks
  const int tid = threadIdx.x;
  const int wave = tid >> 6, lane = tid & 63;
  const int wr = wave >> 1, wc = wave & 1;
  const int l15 = lane & 15, l4 = lane >> 4;

  f32x4 acc[4][4];
  #pragma unroll
  for (int i = 0; i < 4; ++i)
    #pragma unroll
    for (int j = 0; j < 4; ++j) acc[i][j] = (f32x4){0.f, 0.f, 0.f, 0.f};

  auto stage = [&](int buf, int k0) {
    #pragma unroll
    for (int j = 0; j < 2; ++j) {
      int c = j * 256 + tid;
      int row = c >> 2, cs = c & 3;
      int cg = cs ^ (row & 3);
      int cb = j * 256 + (tid & 192);
      gl_lds16(Ab + (size_t)(bm * 128 + row) * DMODEL + k0 + cg * 8, &At[buf][cb * 8]);
      gl_lds16(Wb + (size_t)(bn * 128 + row) * DMODEL + k0 + cg * 8, &Bt[buf][cb * 8]);
    }
  };

  stage(0, 0);
  __syncthreads();

  const int NT = DMODEL / 32;
  for (int it = 0; it < NT; ++it) {
    int cur = it & 1;
    if (it + 1 < NT) stage(cur ^ 1, (it + 1) * 32);

    short8 af[4], bf[4];
    #pragma unroll
    for (int mt = 0; mt < 4; ++mt) {
      int row = wr * 64 + mt * 16 + l15;
      af[mt] = *reinterpret_cast<const short8*>(&At[cur][row * 32 + ((l4 ^ (l15 & 3)) * 8)]);
    }
    #pragma unroll
    for (int nt = 0; nt < 4; ++nt) {
      int row = wc * 64 + nt * 16 + l15;
      bf[nt] = *reinterpret_cast<const short8*>(&Bt[cur][row * 32 + ((l4 ^ (l15 & 3)) * 8)]);
    }
    #pragma unroll
    for (int mt = 0; mt < 4; ++mt)
      #pragma unroll
      for (int nt = 0; nt < 4; ++nt)
        acc[mt][nt] = __builtin_amdgcn_mfma_f32_16x16x32_bf16(af[mt], bf[nt], acc[mt][nt], 0, 0, 0);
    __syncthreads();
  }

  #pragma unroll
  for (int mt = 0; mt < 4; ++mt)
    #pragma unroll
    for (int nt = 0; nt < 4; ++nt) {
      int col = bn * 128 + wc * 64 + nt * 16 + l15;
      float bv = bias[col];
      #pragma unroll
      for (int r = 0; r < 4; ++r) {
        int row = bm * 128 + wr * 64 + mt * 16 + l4 * 4 + r;
        out[(size_t)row * DMODEL + col] = acc[mt][nt][r] + bv;
      }
    }
}

// ---------------------------------------------------------------------------
extern "C" void kernel_launch(void* const* d_in, const int* in_sizes, int n_in,
                              void* d_out, int out_size, void* d_ws, size_t ws_size,
                              hipStream_t stream) {
  const float* values  = (const float*)d_in[0];
  const float* keys    = (const float*)d_in[1];
  const float* queries = (const float*)d_in[2];
  const float* fc_w    = (const float*)d_in[3];
  const float* fc_b    = (const float*)d_in[4];
  float* out = (float*)d_out;

  char* ws = (char*)d_ws;
  const size_t QKV_BYTES = (size_t)NHTOT * SEQ * DHEAD * 2;  // 8 MB each
  unsigned short* Qb = (unsigned short*)(ws);
  unsigned short* Kb = (unsigned short*)(ws + QKV_BYTES);
  unsigned short* Vt = (unsigned short*)(ws + 2 * QKV_BYTES);
  unsigned short* Wb = (unsigned short*)(ws + 3 * QKV_BYTES);
  unsigned short* Ab = (unsigned short*)(ws + 3 * QKV_BYTES + (size_t)DMODEL * DMODEL * 2);

  cvt_qk<<<4096, 256, 0, stream>>>(queries, keys, Qb, Kb);
  vtrans<<<1024, 256, 0, stream>>>(values, Vt);
  cvt_w<<<1024, 256, 0, stream>>>(fc_w, Wb);
  attn_fwd<<<NHTOT * (SEQ / 256), 512, 0, stream>>>(Qb, Kb, Vt, Ab);
  fc_gemm<<<(NBATCH * SEQ / 128) * (DMODEL / 128), 256, 0, stream>>>(Ab, Wb, fc_b, out);
}